// Round 3
// baseline (321.579 us; speedup 1.0000x reference)
//
#include <hip/hip_runtime.h>
#include <math.h>

typedef __bf16  bf16x8 __attribute__((ext_vector_type(8)));
typedef float   f32x4  __attribute__((ext_vector_type(4)));

// async global->LDS, 16B per lane. LDS dest = wave-uniform base + lane*16;
// pass per-lane dest (= base + lane*16) and per-lane global src.
#define GLD_LDS16(dst, src)                                                      \
    __builtin_amdgcn_global_load_lds(                                            \
        (const __attribute__((address_space(1))) unsigned int*)(src),            \
        (__attribute__((address_space(3))) unsigned int*)(dst), 16, 0, 0)

// ---------------------------------------------------------------------------
// Kernel A: global average pool  x[b,ci,64,64] -> pooled[b*256+ci]
// ---------------------------------------------------------------------------
__global__ __launch_bounds__(256) void pool_kernel(const float* __restrict__ x,
                                                   float* __restrict__ pooled) {
    int bc = blockIdx.x;
    const float* p = x + (size_t)bc * 4096;
    int t = threadIdx.x;
    float s = 0.f;
#pragma unroll
    for (int i = 0; i < 16; i++) s += p[t + i * 256];
#pragma unroll
    for (int off = 32; off > 0; off >>= 1) s += __shfl_down(s, off, 64);
    __shared__ float red[4];
    if ((t & 63) == 0) red[t >> 6] = s;
    __syncthreads();
    if (t == 0) pooled[bc] = (red[0] + red[1] + red[2] + red[3]) * (1.f / 4096.f);
}

// ---------------------------------------------------------------------------
// Kernel T: x[b,ci,h,w] fp32 -> xT[b,h,w,ci] bf16 (ci fastest, 512B/pixel)
// block = (h, b); wave handles 8 ci x 64 w per iter; loads coalesced 256B.
// ---------------------------------------------------------------------------
__global__ __launch_bounds__(256) void transpose_kernel(const float* __restrict__ x,
                                                        __bf16* __restrict__ xT) {
    int h = blockIdx.x, b = blockIdx.y;
    int lane = threadIdx.x & 63, wv = threadIdx.x >> 6;
#pragma unroll
    for (int i = 0; i < 8; i++) {
        int cq = i * 4 + wv;                       // ci octet 0..31
        const float* src = x + (((size_t)(b * 256 + cq * 8) * 64 + h) * 64 + lane);
        bf16x8 o;
#pragma unroll
        for (int j = 0; j < 8; j++) o[j] = (__bf16)src[(size_t)j * 4096];
        *(bf16x8*)(xT + (((size_t)(b * 64 + h) * 64 + lane) * 256 + cq * 8)) = o;
    }
}

// ---------------------------------------------------------------------------
// Kernel B: routing heads -> S[b,n,9,9] = lambda * R(theta); BN fold
// ---------------------------------------------------------------------------
__global__ __launch_bounds__(256) void routing_kernel(
    const float* __restrict__ pooled,
    const float* __restrict__ w_lambda, const float* __restrict__ w_theta,
    const float* __restrict__ bn_gamma, const float* __restrict__ bn_beta,
    const float* __restrict__ bn_mean,  const float* __restrict__ bn_var,
    float* __restrict__ S, float* __restrict__ bnscale, float* __restrict__ bnshift) {
    int t = threadIdx.x;
    if (t < 256) {
        float inv = rsqrtf(bn_var[t] + 1e-5f);
        float sc = bn_gamma[t] * inv;
        bnscale[t] = sc;
        bnshift[t] = bn_beta[t] - bn_mean[t] * sc;
    }
    if (t < 64) {
        int b = t >> 2, n = t & 3;
        float zl = 0.f, zt = 0.f;
        for (int ci = 0; ci < 256; ci++) {
            float p = pooled[b * 256 + ci];
            zl += p * w_lambda[ci * 4 + n];
            zt += p * w_theta[ci * 4 + n];
        }
        float lam = 1.f / (1.f + expf(-zl));
        float th  = 3.14159265358979323846f * (zt / (1.f + fabsf(zt)));
        float xc = cosf(th), ys = sinf(th);
        float a = xc - ys, bb = xc * ys, c = xc + ys;
        float R[9][9];
#pragma unroll
        for (int i = 0; i < 9; i++)
#pragma unroll
            for (int j = 0; j < 9; j++) R[i][j] = 0.f;
        if (th >= 0.f) {
            R[0][0] = a;       R[0][1] = 1 - a;
            R[1][1] = xc - bb; R[1][2] = bb;       R[1][4] = 1 - c + bb; R[1][5] = ys - bb;
            R[2][2] = a;       R[2][5] = 1 - a;
            R[3][0] = bb;      R[3][1] = ys - bb;  R[3][3] = xc - bb;    R[3][4] = 1 - c + bb;
            R[4][4] = 1.f;
            R[5][4] = 1 - c + bb; R[5][5] = xc - bb; R[5][7] = ys - bb;  R[5][8] = bb;
            R[6][3] = 1 - a;   R[6][6] = a;
            R[7][3] = ys - bb; R[7][4] = 1 - c + bb; R[7][6] = bb;       R[7][7] = xc - bb;
            R[8][7] = 1 - a;   R[8][8] = a;
        } else {
            R[0][0] = c;       R[0][3] = 1 - c;
            R[1][0] = -bb;     R[1][1] = xc + bb;  R[1][3] = bb - ys;    R[1][4] = 1 - a - bb;
            R[2][1] = 1 - c;   R[2][2] = c;
            R[3][3] = xc + bb; R[3][4] = 1 - a - bb; R[3][6] = -bb;      R[3][7] = bb - ys;
            R[4][4] = 1.f;
            R[5][1] = bb - ys; R[5][2] = -bb;      R[5][4] = 1 - a - bb; R[5][5] = xc + bb;
            R[6][6] = c;       R[6][7] = 1 - c;
            R[7][4] = 1 - a - bb; R[7][5] = bb - ys; R[7][7] = xc + bb;  R[7][8] = -bb;
            R[8][5] = 1 - c;   R[8][8] = c;
        }
        float* Sp = S + (b * 4 + n) * 81;
#pragma unroll
        for (int p = 0; p < 9; p++)
#pragma unroll
            for (int q = 0; q < 9; q++) Sp[p * 9 + q] = lam * R[p][q];
    }
}

// ---------------------------------------------------------------------------
// Kernel C: rotated weights  rwq[b][p][co][ci] bf16.
// One block per co (256 blocks): coalesced weight loads once, all 16 b.
// S read via uniform (scalar) global loads; weight frags in registers.
// ---------------------------------------------------------------------------
__global__ __launch_bounds__(256) void rotw_kernel(const float* __restrict__ weight,
                                                   const float* __restrict__ S,
                                                   __bf16* __restrict__ rwq) {
    __shared__ float wlds[4][2304];      // [n][ci*9+q]
    int co = blockIdx.x;
    int t = threadIdx.x;
#pragma unroll
    for (int n = 0; n < 4; n++) {
        const float* wp = weight + ((size_t)n * 256 + co) * 2304;
        for (int i = t; i < 2304; i += 256) wlds[n][i] = wp[i];
    }
    __syncthreads();
    int ci = t;
    float w[4][9];
#pragma unroll
    for (int n = 0; n < 4; n++)
#pragma unroll
        for (int q = 0; q < 9; q++) w[n][q] = wlds[n][ci * 9 + q];
    for (int b = 0; b < 16; b++) {
#pragma unroll
        for (int p = 0; p < 9; p++) {
            float s = 0.f;
#pragma unroll
            for (int n = 0; n < 4; n++) {
                const float* sp = S + (b * 4 + n) * 81 + p * 9;   // uniform -> s_load
#pragma unroll
                for (int q = 0; q < 9; q++) s += sp[q] * w[n][q];
            }
            rwq[(((size_t)b * 9 + p) * 256 + co) * 256 + ci] = (__bf16)s;
        }
    }
}

// ---------------------------------------------------------------------------
// Kernel D: implicit-GEMM conv + fused BN/ReLU.
// xs[rr][kq][col][8] / as3[dw][kq][co][8]: 4-dword lane stride on ds_read_b128
// -> conflict-free (8 accesses/bank). All staging via global_load_lds (async,
// no LDS-write instrs, no VALU convert).
// ---------------------------------------------------------------------------
__global__ __launch_bounds__(256, 4) void conv_kernel(
    const __bf16* __restrict__ xT, const __bf16* __restrict__ rwq,
    const float* __restrict__ bnscale, const float* __restrict__ bnshift,
    float* __restrict__ out) {
    __shared__ __attribute__((aligned(16))) __bf16 xs[6][4][66][8];   // 25344 B
    __shared__ __attribute__((aligned(16))) __bf16 as3[3][4][64][8];  // 12288 B

    const int t    = threadIdx.x;
    const int lane = t & 63;
    const int wv   = t >> 6;       // wave id = output row within tile
    const int l15  = lane & 15;
    const int kq4  = lane >> 4;

    const int h0  = blockIdx.x * 4;
    const int co0 = blockIdx.y * 64;
    const int b   = blockIdx.z;

    f32x4 acc[4][4];
#pragma unroll
    for (int m = 0; m < 4; m++)
#pragma unroll
        for (int n = 0; n < 4; n++) acc[m][n] = (f32x4){0.f, 0.f, 0.f, 0.f};

    // halo cols 0 and 65 (x w = -1 / 64): always zero, write once
    if (t < 192) {
        int rr = t / 32, kq = (t % 32) >> 3, j = t & 7;
        xs[rr][kq][0][j]  = (__bf16)0.f;
        xs[rr][kq][65][j] = (__bf16)0.f;
    }
    const uint4 zero4 = {0u, 0u, 0u, 0u};

    for (int ci0 = 0; ci0 < 256; ci0 += 32) {
        __syncthreads();                 // prev chunk compute done before xs overwrite
        // stage x: 24 units (rr,kq); wave handles 6. lane = w 0..63 -> col 1+lane
#pragma unroll
        for (int u = wv * 6; u < wv * 6 + 6; u++) {
            int rr = u >> 2, kq = u & 3;
            int hh = h0 - 1 + rr;
            if (hh >= 0 && hh < 64) {
                const __bf16* src = xT + (((size_t)(b * 64 + hh) * 64 + lane) * 256 + ci0 + kq * 8);
                GLD_LDS16(&xs[rr][kq][1 + lane][0], src);
            } else {
                *(uint4*)&xs[rr][kq][1 + lane][0] = zero4;   // zero row (uniform branch)
            }
        }
        for (int dh = 0; dh < 3; dh++) {
            __syncthreads();             // prev dh's as3 consumed (and dh=0: no-op for xs)
            // stage weights: 12 units (dw,kq); wave handles 3. lane = co
#pragma unroll
            for (int u = wv * 3; u < wv * 3 + 3; u++) {
                int dw = u >> 2, kq = u & 3;
                const __bf16* src = rwq +
                    ((((size_t)b * 9 + dh * 3 + dw) * 256 + co0 + lane) * 256 + ci0 + kq * 8);
                GLD_LDS16(&as3[dw][kq][lane][0], src);
            }
            __syncthreads();             // xs + as3 ready (barrier drains vmcnt)
#pragma unroll
            for (int dw = 0; dw < 3; dw++) {
                bf16x8 af[4];
#pragma unroll
                for (int m = 0; m < 4; m++)
                    af[m] = *(const bf16x8*)&as3[dw][kq4][m * 16 + l15][0];
#pragma unroll
                for (int nt = 0; nt < 4; nt++) {
                    bf16x8 bfr = *(const bf16x8*)&xs[wv + dh][kq4][nt * 16 + l15 + dw][0];
#pragma unroll
                    for (int m = 0; m < 4; m++)
                        acc[m][nt] = __builtin_amdgcn_mfma_f32_16x16x32_bf16(
                            af[m], bfr, acc[m][nt], 0, 0, 0);
                }
            }
        }
    }

    // epilogue: BN + ReLU. D layout: row(co) = kq4*4+reg, col(w) = l15
    const int h = h0 + wv;
#pragma unroll
    for (int m = 0; m < 4; m++) {
#pragma unroll
        for (int reg = 0; reg < 4; reg++) {
            int co = co0 + m * 16 + kq4 * 4 + reg;
            float sc = bnscale[co], sh = bnshift[co];
#pragma unroll
            for (int nt = 0; nt < 4; nt++) {
                int w = nt * 16 + l15;
                float v = acc[m][nt][reg] * sc + sh;
                out[(((size_t)b * 256 + co) * 64 + h) * 64 + w] = v > 0.f ? v : 0.f;
            }
        }
    }
}

// ---------------------------------------------------------------------------
extern "C" void kernel_launch(void* const* d_in, const int* in_sizes, int n_in,
                              void* d_out, int out_size, void* d_ws, size_t ws_size,
                              hipStream_t stream) {
    const float* x        = (const float*)d_in[0];
    const float* weight   = (const float*)d_in[1];
    const float* w_lambda = (const float*)d_in[2];
    const float* w_theta  = (const float*)d_in[3];
    const float* bn_gamma = (const float*)d_in[4];
    const float* bn_beta  = (const float*)d_in[5];
    const float* bn_mean  = (const float*)d_in[6];
    const float* bn_var   = (const float*)d_in[7];
    float* out = (float*)d_out;

    char* ws = (char*)d_ws;
    float*  pooled  = (float*)(ws);                    // 4096 f
    float*  S       = (float*)(ws + 16384);            // 5184 f
    float*  bnscale = (float*)(ws + 40960);            // 256 f
    float*  bnshift = (float*)(ws + 45056);            // 256 f
    __bf16* xT      = (__bf16*)(ws + 49152);           // 16*64*64*256 bf16 = 33.5 MB
    __bf16* rwq     = (__bf16*)(ws + 49152 + 33554432); // 16*9*256*256 bf16 = 18.9 MB

    pool_kernel<<<4096, 256, 0, stream>>>(x, pooled);
    transpose_kernel<<<dim3(64, 16), 256, 0, stream>>>(x, xT);
    routing_kernel<<<1, 256, 0, stream>>>(pooled, w_lambda, w_theta,
                                          bn_gamma, bn_beta, bn_mean, bn_var,
                                          S, bnscale, bnshift);
    rotw_kernel<<<256, 256, 0, stream>>>(weight, S, rwq);
    conv_kernel<<<dim3(16, 4, 16), 256, 0, stream>>>(xT, rwq, bnscale, bnshift, out);
}